// Round 11
// baseline (731.792 us; speedup 1.0000x reference)
//
#include <hip/hip_runtime.h>
#include <math.h>

#define T_SEQ   1000
#define BATCH   8
#define DMODEL  512
#define NHEAD   8
#define DHEAD   64
#define FFDIM   2048
#define NLAYER  4
#define MROWS   (BATCH * T_SEQ)   // 8000
#define TCHUNK  25
#define QKS     1024              // Q|K row stride (elements)
#define VTS     1024              // Vt row stride (elements, padded from 1000)

typedef __bf16 bf16x8 __attribute__((ext_vector_type(8)));
typedef __bf16 bf16x4 __attribute__((ext_vector_type(4)));
typedef float  f32x4  __attribute__((ext_vector_type(4)));
typedef float  f32x16 __attribute__((ext_vector_type(16)));

#define GL2LDS(g, l) \
    __builtin_amdgcn_global_load_lds((const __attribute__((address_space(1))) void*)(g), \
                                     (__attribute__((address_space(3))) void*)(l), 16, 0, 0)

// ---------------------------------------------------------------------------
__global__ __launch_bounds__(256)
void f2bf(const float* __restrict__ in, __bf16* __restrict__ out)
{
    int i = (blockIdx.x * 256 + threadIdx.x) * 4;
    float4 v = *(const float4*)(in + i);
    bf16x4 o;
    o[0] = (__bf16)v.x; o[1] = (__bf16)v.y; o[2] = (__bf16)v.z; o[3] = (__bf16)v.w;
    *(bf16x4*)(out + i) = o;
}

// ---------------------------------------------------------------------------
// bf16 MFMA GEMM: C(MxN) = A(MxK) @ B(NxK)^T + bias.
// TM x 128 tile, BK=64, 4 waves (2x2), 16x16x32 MFMA.
// TM=64 : 3-buffer counted vmcnt(6) pipeline (proven R7 config), 72 KB LDS.
// TM=128: m97 geometry (64x64/wave, 32 MFMA/K-step — 2x density), 2-buffer
//         issue-early pipeline (stage(t+1) BEFORE compute(t), vmcnt(0) after),
//         64 KB LDS. For the large-grid GEMMs (QKV, FF1).
// T2 both-sides swizzle, T5 setprio, T1 bijective XCD swizzle (m204).
// MODE 0: bf16 row-major out (stride N), optional RELU.
// MODE 1: + fused sinusoidal PE (embed; N == DMODEL).
// MODE 2: QKV split — gc<1024 -> qkb[gr*QKS+gc]; gc>=1024 -> Vt transposed.
// ---------------------------------------------------------------------------
template<int TM, int MODE, bool RELU>
__global__ __launch_bounds__(256)
void gemm_bf16(const __bf16* __restrict__ A, const __bf16* __restrict__ B,
               const float* __restrict__ bias, __bf16* __restrict__ Cb,
               __bf16* __restrict__ Vt, int M, int N, int K)
{
    constexpr int NBUF = (TM == 64) ? 3 : 2;
    constexpr int PA   = TM / 32;        // A staging passes (TM*128B / 4096B)
    constexpr int MR   = TM / 32;        // m-fragments per wave
    __shared__ __align__(16) __bf16 As[NBUF][TM * 64];
    __shared__ __align__(16) __bf16 Bs[NBUF][128 * 64];

    const int tid  = threadIdx.x;
    const int lane = tid & 63;
    const int w    = tid >> 6;
    const int wr   = w >> 1, wc = w & 1;

    // T1: bijective XCD swizzle (m204); consecutive work-ids share the A band.
    const int gx  = gridDim.x;
    const int nwg = gx * gridDim.y;
    const int bid = blockIdx.y * gx + blockIdx.x;
    const int qc  = nwg >> 3, rc = nwg & 7;
    const int xcd = bid & 7, idx = bid >> 3;
    const int swz = (xcd < rc) ? xcd * (qc + 1) + idx
                               : rc * (qc + 1) + (xcd - rc) * qc + idx;
    const int row0 = (swz / gx) * TM;
    const int col0 = (swz % gx) * 128;

    size_t aoffg[PA], boffg[4];
    int    ldsoA[PA], ldsoB[4];
    #pragma unroll
    for (int p = 0; p < PA; ++p) {
        const int bo = p * 4096 + tid * 16;
        const int r  = bo >> 7;
        const int cs = (bo & 127) ^ ((r & 7) << 4);
        int ga = row0 + r; if (ga > M - 1) ga = M - 1;   // M-tail clamp
        aoffg[p] = (size_t)ga * K * 2 + cs;
        ldsoA[p] = bo;
    }
    #pragma unroll
    for (int p = 0; p < 4; ++p) {
        const int bo = p * 4096 + tid * 16;
        const int r  = bo >> 7;
        const int cs = (bo & 127) ^ ((r & 7) << 4);
        boffg[p] = (size_t)(col0 + r) * K * 2 + cs;
        ldsoB[p] = bo;
    }

    f32x4 acc[MR][4];
    #pragma unroll
    for (int m = 0; m < MR; ++m)
        #pragma unroll
        for (int n = 0; n < 4; ++n) acc[m][n] = (f32x4)0.f;

    const char* gA = (const char*)A;
    const char* gB = (const char*)B;
    const int nt = K >> 6;

    auto STAGE = [&](int tt, int buf) {
        const size_t kb = (size_t)tt << 7;
        char* lA = (char*)As[buf];
        char* lB = (char*)Bs[buf];
        #pragma unroll
        for (int p = 0; p < PA; ++p) GL2LDS(gA + aoffg[p] + kb, lA + ldsoA[p]);
        #pragma unroll
        for (int p = 0; p < 4;  ++p) GL2LDS(gB + boffg[p] + kb, lB + ldsoB[p]);
    };

    // prologue
    STAGE(0, 0);
    if (NBUF == 3) {
        STAGE(1, 1);
        asm volatile("s_waitcnt vmcnt(6)" ::: "memory");   // tile 0's 6 loads done
    } else {
        asm volatile("s_waitcnt vmcnt(0)" ::: "memory");
    }
    __builtin_amdgcn_s_barrier();
    __builtin_amdgcn_sched_barrier(0);

    int bc = 0, bn = NBUF - 1;
    for (int t = 0; t < nt; ++t) {
        if (t + NBUF - 1 < nt) STAGE(t + NBUF - 1, bn);
        const char* as = (const char*)As[bc];
        const char* bs = (const char*)Bs[bc];
        __builtin_amdgcn_s_setprio(1);
        #pragma unroll
        for (int ks = 0; ks < 2; ++ks) {
            bf16x8 af[MR], bfr[4];
            const int cb = ks * 64 + (lane >> 4) * 16;
            #pragma unroll
            for (int m = 0; m < MR; ++m) {
                const int rr = wr * (TM / 2) + m * 16 + (lane & 15);
                af[m] = *(const bf16x8*)(as + rr * 128 + (cb ^ ((rr & 7) << 4)));
            }
            #pragma unroll
            for (int n = 0; n < 4; ++n) {
                const int rr = wc * 64 + n * 16 + (lane & 15);
                bfr[n] = *(const bf16x8*)(bs + rr * 128 + (cb ^ ((rr & 7) << 4)));
            }
            #pragma unroll
            for (int m = 0; m < MR; ++m)
                #pragma unroll
                for (int n = 0; n < 4; ++n)
                    acc[m][n] = __builtin_amdgcn_mfma_f32_16x16x32_bf16(af[m], bfr[n], acc[m][n], 0, 0, 0);
        }
        __builtin_amdgcn_s_setprio(0);
        if (NBUF == 3 && t + 2 < nt) { asm volatile("s_waitcnt vmcnt(6)" ::: "memory"); }
        else                         { asm volatile("s_waitcnt vmcnt(0)" ::: "memory"); }
        __builtin_amdgcn_s_barrier();
        __builtin_amdgcn_sched_barrier(0);
        bc = (bc + 1 == NBUF) ? 0 : bc + 1;
        bn = (bn + 1 == NBUF) ? 0 : bn + 1;
    }

    const int crow = (lane >> 4) * 4;
    const int ccol = lane & 15;
    #pragma unroll
    for (int n = 0; n < 4; ++n) {
        const int gc = col0 + wc * 64 + n * 16 + ccol;
        const float bv = bias[gc];
        float freq = 0.f;
        if (MODE == 1) freq = __expf((float)(gc & ~1) * (-9.210340371976184f / (float)DMODEL));
        #pragma unroll
        for (int m = 0; m < MR; ++m) {
            const int gr0 = row0 + wr * (TM / 2) + m * 16 + crow;
            #pragma unroll
            for (int r = 0; r < 4; ++r) {
                const int gr = gr0 + r;
                if (gr >= M) continue;
                float v = acc[m][n][r] + bv;
                if (MODE == 1) {
                    const int tt = gr % T_SEQ;
                    const float ang = (float)tt * freq;
                    v += (gc & 1) ? __cosf(ang) : __sinf(ang);
                }
                if (RELU) v = fmaxf(v, 0.f);
                if (MODE == 2) {
                    const int bidx = gr / T_SEQ;
                    const int tt   = gr - bidx * T_SEQ;
                    if (gc < 1024) {
                        Cb[(size_t)gr * QKS + gc] = (__bf16)v;
                    } else {
                        Vt[((size_t)(bidx * DMODEL + (gc - 1024)) << 10) + tt] = (__bf16)v;
                    }
                } else {
                    Cb[(size_t)gr * N + gc] = (__bf16)v;
                }
            }
        }
    }
}

// ---------------------------------------------------------------------------
// MFMA flash attention v2.1: one WAVE per block (64 thr, 1024 blocks);
// head pair (ph, 7-ph) per wave => constant work. QK^T swapped (col=q);
// PV computes O^T = mfma(V^T-frag, P^T-frag) from transposed Vt.
// ---------------------------------------------------------------------------
__global__ __launch_bounds__(64)
void attn_mfma(const __bf16* __restrict__ qkb, const __bf16* __restrict__ vt,
               __bf16* __restrict__ o)
{
    const int wv   = blockIdx.x;
    const int lane = threadIdx.x;
    const int ph   = wv & 3;
    const int qt   = (wv >> 2) & 31;
    const int b    = wv >> 7;
    const int qb   = qt * 32;
    const int half = lane >> 5;
    const int ql   = lane & 31;
    const int i    = qb + ql;
    const int iq   = (i < T_SEQ) ? i : (T_SEQ - 1);
    const float C2 = 0.125f * 1.44269504089f;

    const __bf16* QKb = qkb + (size_t)b * T_SEQ * QKS;

    #pragma unroll
    for (int jb = 0; jb < 2; ++jb) {
        const int hh = jb ? (7 - ph) : ph;
        const __bf16* Q = QKb + hh * DHEAD;
        const __bf16* K = Q + 512;
        const __bf16* Vb = vt + (((size_t)b * DMODEL + hh * DHEAD) << 10);

        bf16x8 qf[4];
        {
            const __bf16* qrow = Q + (size_t)iq * QKS + half * 8;
            #pragma unroll
            for (int ds = 0; ds < 4; ++ds)
                qf[ds] = *(const bf16x8*)(qrow + ds * 16);
        }

        const int w = 25 * (hh + 1);
        const int kb_lo = (qb - w > 0 ? qb - w : 0) & ~31;
        const int kb_hi = (qb + 31 + w < T_SEQ - 1) ? (qb + 31 + w) : (T_SEQ - 1);
        const int spanv = (2 * w < T_SEQ - 1 - i + w) ? 2 * w : (T_SEQ - 1 - i + w);
        const unsigned span = (unsigned)spanv;

        float m2 = -1e9f, l = 0.f;
        f32x16 oa0 = (f32x16)0.f, oa1 = (f32x16)0.f;

        for (int kb = kb_lo; kb <= kb_hi; kb += 32) {
            f32x16 sv = (f32x16)0.f;
            {
                int krow = kb + ql; if (krow > T_SEQ - 1) krow = T_SEQ - 1;
                const __bf16* kr = K + (size_t)krow * QKS + half * 8;
                #pragma unroll
                for (int ds = 0; ds < 4; ++ds) {
                    bf16x8 kf = *(const bf16x8*)(kr + ds * 16);
                    sv = __builtin_amdgcn_mfma_f32_32x32x16_bf16(kf, qf[ds], sv, 0, 0, 0);
                }
            }

            const bool full = (kb >= qb + 31 - w) && (kb + 31 <= qb + w)
                           && (kb + 31 <= T_SEQ - 1);
            float s2[16];
            if (full) {
                #pragma unroll
                for (int r = 0; r < 16; ++r) s2[r] = sv[r] * C2;
            } else {
                const int base = kb - i + w;
                #pragma unroll
                for (int r = 0; r < 16; ++r) {
                    const int kr = (r & 3) + 8 * (r >> 2) + 4 * half;
                    const unsigned jrel = (unsigned)(base + kr);
                    s2[r] = (jrel <= span) ? sv[r] * C2 : -1e9f;
                }
            }

            float mx = s2[0];
            #pragma unroll
            for (int r = 1; r < 16; ++r) mx = fmaxf(mx, s2[r]);
            mx = fmaxf(mx, __shfl_xor(mx, 32, 64));

            if (!__all(mx <= m2 + 8.0f)) {
                const float mnew  = fmaxf(m2, mx);
                const float scale = exp2f(m2 - mnew);
                m2 = mnew;
                l *= scale;
                oa0 *= scale;
                oa1 *= scale;
            }

            float p[16];
            float ps = 0.f;
            #pragma unroll
            for (int r = 0; r < 16; ++r) { p[r] = exp2f(s2[r] - m2); ps += p[r]; }
            ps += __shfl_xor(ps, 32, 64);
            l += ps;

            unsigned pk[8];
            #pragma unroll
            for (int t = 0; t < 8; ++t) {
                union { unsigned u; __bf16 h[2]; } cv;
                cv.h[0] = (__bf16)p[2 * t];
                cv.h[1] = (__bf16)p[2 * t + 1];
                pk[t] = cv.u;
            }
            unsigned y[8];
            #pragma unroll
            for (int t = 0; t < 8; ++t)
                y[t] = (unsigned)__shfl_xor((int)pk[t], 32, 64);

            union { unsigned u[4]; bf16x8 v; } pa0, pa1;
            if (half == 0) {
                pa0.u[0] = pk[0]; pa0.u[1] = pk[1]; pa0.u[2] = y[0];  pa0.u[3] = y[1];
                pa1.u[0] = pk[4]; pa1.u[1] = pk[5]; pa1.u[2] = y[4];  pa1.u[3] = y[5];
            } else {
                pa0.u[0] = y[2];  pa0.u[1] = y[3];  pa0.u[2] = pk[2]; pa0.u[3] = pk[3];
                pa1.u[0] = y[6];  pa1.u[1] = y[7];  pa1.u[2] = pk[6]; pa1.u[3] = pk[7];
            }

            #pragma unroll
            for (int ks = 0; ks < 2; ++ks) {
                const int kc = kb + ks * 16 + half * 8;
                #pragma unroll
                for (int dh = 0; dh < 2; ++dh) {
                    const bf16x8 vf = *(const bf16x8*)(Vb + (((size_t)(dh * 32 + ql)) << 10) + kc);
                    if (dh == 0)
                        oa0 = __builtin_amdgcn_mfma_f32_32x32x16_bf16(vf, ks ? pa1.v : pa0.v, oa0, 0, 0, 0);
                    else
                        oa1 = __builtin_amdgcn_mfma_f32_32x32x16_bf16(vf, ks ? pa1.v : pa0.v, oa1, 0, 0, 0);
                }
            }
        }

        if (i < T_SEQ) {
            const float ri = 1.f / l;
            __bf16* orow = o + (size_t)(b * T_SEQ + i) * DMODEL + hh * DHEAD;
            #pragma unroll
            for (int g = 0; g < 4; ++g) {
                bf16x4 v0, v1;
                #pragma unroll
                for (int r = 0; r < 4; ++r) {
                    v0[r] = (__bf16)(oa0[g * 4 + r] * ri);
                    v1[r] = (__bf16)(oa1[g * 4 + r] * ri);
                }
                *(bf16x4*)(orow + g * 8 + half * 4)      = v0;
                *(bf16x4*)(orow + 32 + g * 8 + half * 4) = v1;
            }
        }
    }
}

// ---------------------------------------------------------------------------
// h = LayerNorm(h + t) * g + b — bf16 residual stream, fp32 math.
// ---------------------------------------------------------------------------
__global__ __launch_bounds__(256)
void add_ln(__bf16* __restrict__ hb, const __bf16* __restrict__ tbuf,
            const float* __restrict__ g, const float* __restrict__ b)
{
    const int row  = blockIdx.x * 4 + (threadIdx.x >> 6);
    const int lane = threadIdx.x & 63;
    __bf16*       hp = hb   + (size_t)row * DMODEL + lane * 8;
    const __bf16* tp = tbuf + (size_t)row * DMODEL + lane * 8;

    bf16x8 hv = *(const bf16x8*)hp;
    bf16x8 tv = *(const bf16x8*)tp;
    float xv[8];
    #pragma unroll
    for (int j = 0; j < 8; ++j) xv[j] = (float)hv[j] + (float)tv[j];

    float s = 0.f;
    #pragma unroll
    for (int j = 0; j < 8; ++j) s += xv[j];
    #pragma unroll
    for (int off = 32; off >= 1; off >>= 1) s += __shfl_xor(s, off, 64);
    float mean = s * (1.f / DMODEL);

    float vs = 0.f;
    #pragma unroll
    for (int j = 0; j < 8; ++j) { float d = xv[j] - mean; vs += d * d; }
    #pragma unroll
    for (int off = 32; off >= 1; off >>= 1) vs += __shfl_xor(vs, off, 64);
    float rstd = rsqrtf(vs * (1.f / DMODEL) + 1e-5f);

    float4 g0 = *(const float4*)(g + lane * 8);
    float4 g1 = *(const float4*)(g + lane * 8 + 4);
    float4 b0 = *(const float4*)(b + lane * 8);
    float4 b1 = *(const float4*)(b + lane * 8 + 4);
    float gg[8] = {g0.x, g0.y, g0.z, g0.w, g1.x, g1.y, g1.z, g1.w};
    float bb[8] = {b0.x, b0.y, b0.z, b0.w, b1.x, b1.y, b1.z, b1.w};

    bf16x8 ob;
    #pragma unroll
    for (int j = 0; j < 8; ++j)
        ob[j] = (__bf16)((xv[j] - mean) * rstd * gg[j] + bb[j]);
    *(bf16x8*)hp = ob;
}

// ---------------------------------------------------------------------------
__global__ __launch_bounds__(256)
void pool_p1(const __bf16* __restrict__ hb, float* __restrict__ part)
{
    const int bb  = blockIdx.x;
    const int tc  = blockIdx.y;
    const int tid = threadIdx.x;
    const int t0  = tc * (T_SEQ / TCHUNK);
    const __bf16* p = hb + ((size_t)bb * T_SEQ + t0) * DMODEL;

    float mx0 = -3.4e38f, mx1 = -3.4e38f;
    for (int t = 0; t < T_SEQ / TCHUNK; ++t) {
        mx0 = fmaxf(mx0, (float)p[(size_t)t * DMODEL + tid]);
        mx1 = fmaxf(mx1, (float)p[(size_t)t * DMODEL + 256 + tid]);
    }
    float* q = part + ((size_t)bb * TCHUNK + tc) * DMODEL;
    q[tid]       = mx0;
    q[tid + 256] = mx1;
}

// ---------------------------------------------------------------------------
__global__ __launch_bounds__(256)
void pool_p2(const float* __restrict__ part, const float* __restrict__ Wcls,
             const float* __restrict__ bcls, float* __restrict__ out)
{
    __shared__ float pooled[DMODEL];
    __shared__ float logits[8];
    const int bb  = blockIdx.x;
    const int tid = threadIdx.x;

    const float* q = part + (size_t)bb * TCHUNK * DMODEL;
    #pragma unroll
    for (int u = 0; u < 2; ++u) {
        const int d = tid + u * 256;
        float mx = -3.4e38f;
        for (int c = 0; c < TCHUNK; ++c) mx = fmaxf(mx, q[(size_t)c * DMODEL + d]);
        pooled[d] = mx;
    }
    __syncthreads();

    const int cls  = tid >> 5;
    const int lsub = tid & 31;
    const float* wr = Wcls + cls * DMODEL;
    float s = 0.f;
    #pragma unroll
    for (int u = 0; u < 16; ++u) {
        const int d = lsub + u * 32;
        s = fmaf(pooled[d], wr[d], s);
    }
    #pragma unroll
    for (int off = 16; off >= 1; off >>= 1) s += __shfl_xor(s, off, 32);
    if (lsub == 0) logits[cls] = s + bcls[cls];
    __syncthreads();

    if (tid == 0) {
        float mx = logits[0];
        for (int c = 1; c < 8; ++c) mx = fmaxf(mx, logits[c]);
        float se = 0.f;
        for (int c = 0; c < 8; ++c) se += expf(logits[c] - mx);
        float lse = logf(se) + mx;
        for (int c = 0; c < 8; ++c) out[bb * 8 + c] = logits[c] - lse;
    }
}

// ---------------------------------------------------------------------------
extern "C" void kernel_launch(void* const* d_in, const int* in_sizes, int n_in,
                              void* d_out, int out_size, void* d_ws, size_t ws_size,
                              hipStream_t stream)
{
    const float* x    = (const float*)d_in[0];
    const float* Wemb = (const float*)d_in[1];
    const float* bemb = (const float*)d_in[2];
    const float* Wqkv = (const float*)d_in[3];
    const float* bqkv = (const float*)d_in[4];
    const float* Wo   = (const float*)d_in[5];
    const float* bo   = (const float*)d_in[6];
    const float* W1   = (const float*)d_in[7];
    const float* b1f  = (const float*)d_in[8];
    const float* W2   = (const float*)d_in[9];
    const float* b2f  = (const float*)d_in[10];
    const float* g1   = (const float*)d_in[11];
    const float* be1  = (const float*)d_in[12];
    const float* g2   = (const float*)d_in[13];
    const float* be2  = (const float*)d_in[14];
    const float* Wcls = (const float*)d_in[15];
    const float* bcls = (const float*)d_in[16];
    float* out = (float*)d_out;

    // -------- workspace layout (all bf16 except pool partials) --------
    __bf16* hb   = (__bf16*)d_ws;                      // 8000x512
    __bf16* qkb  = hb   + (size_t)MROWS * DMODEL;      // 8000x1024 (Q|K)
    __bf16* vtb  = qkb  + (size_t)MROWS * QKS;         // 8x512x1024 transposed V
    __bf16* attb = vtb  + (size_t)BATCH * DMODEL * VTS;// 8000x512
    __bf16* ff1b = attb + (size_t)MROWS * DMODEL;      // 8000x2048
    __bf16* tmpB = ff1b + (size_t)MROWS * FFDIM;       // 8000x512
    __bf16* xb   = tmpB + (size_t)MROWS * DMODEL;      // 8000x256
    __bf16* wEmb = xb   + (size_t)MROWS * 256;
    __bf16* wQKV = wEmb + 512 * 256;
    __bf16* wWo  = wQKV + (size_t)NLAYER * 3 * DMODEL * DMODEL;
    __bf16* wW1  = wWo  + (size_t)NLAYER * DMODEL * DMODEL;
    __bf16* wW2  = wW1  + (size_t)NLAYER * FFDIM * DMODEL;
    float*  partF = (float*)(wW2 + (size_t)NLAYER * DMODEL * FFDIM); // 8x25x512

    dim3 blk(256);

    f2bf<<<dim3(MROWS * 256 / 1024), blk, 0, stream>>>(x, xb);
    f2bf<<<dim3(512 * 256 / 1024), blk, 0, stream>>>(Wemb, wEmb);
    f2bf<<<dim3(NLAYER * 3 * DMODEL * DMODEL / 1024), blk, 0, stream>>>(Wqkv, wQKV);
    f2bf<<<dim3(NLAYER * DMODEL * DMODEL / 1024), blk, 0, stream>>>(Wo, wWo);
    f2bf<<<dim3(NLAYER * FFDIM * DMODEL / 1024), blk, 0, stream>>>(W1, wW1);
    f2bf<<<dim3(NLAYER * DMODEL * FFDIM / 1024), blk, 0, stream>>>(W2, wW2);

    // embed + fused PE -> hb (small N: TM=64 path)
    gemm_bf16<64, 1, false><<<dim3(4, 125), blk, 0, stream>>>(
        xb, wEmb, bemb, hb, nullptr, MROWS, DMODEL, 256);

    for (int l = 0; l < NLAYER; ++l) {
        // QKV: N=1536, TM=128 high-density path, grid (12,63)=756 blocks
        gemm_bf16<128, 2, false><<<dim3(12, 63), blk, 0, stream>>>(
            hb, wQKV + (size_t)l * 3 * DMODEL * DMODEL, bqkv + (size_t)l * 3 * DMODEL,
            qkb, vtb, MROWS, 3 * DMODEL, DMODEL);
        attn_mfma<<<dim3(1024), dim3(64), 0, stream>>>(qkb, vtb, attb);
        // Wo: N=512, TM=64
        gemm_bf16<64, 0, false><<<dim3(4, 125), blk, 0, stream>>>(
            attb, wWo + (size_t)l * DMODEL * DMODEL, bo + (size_t)l * DMODEL,
            tmpB, nullptr, MROWS, DMODEL, DMODEL);
        add_ln<<<dim3(MROWS / 4), blk, 0, stream>>>(
            hb, tmpB, g1 + (size_t)l * DMODEL, be1 + (size_t)l * DMODEL);
        // FF1: N=2048, TM=128, grid (16,63)=1008 blocks
        gemm_bf16<128, 0, true><<<dim3(16, 63), blk, 0, stream>>>(
            hb, wW1 + (size_t)l * FFDIM * DMODEL, b1f + (size_t)l * FFDIM,
            ff1b, nullptr, MROWS, FFDIM, DMODEL);
        // FF2: N=512, K=2048, TM=64
        gemm_bf16<64, 0, false><<<dim3(4, 125), blk, 0, stream>>>(
            ff1b, wW2 + (size_t)l * DMODEL * FFDIM, b2f + (size_t)l * DMODEL,
            tmpB, nullptr, MROWS, DMODEL, FFDIM);
        add_ln<<<dim3(MROWS / 4), blk, 0, stream>>>(
            hb, tmpB, g2 + (size_t)l * DMODEL, be2 + (size_t)l * DMODEL);
    }

    pool_p1<<<dim3(BATCH, TCHUNK), blk, 0, stream>>>(hb, partF);
    pool_p2<<<dim3(BATCH), blk, 0, stream>>>(partF, Wcls, bcls, out);
}

// Round 12
// 604.118 us; speedup vs baseline: 1.2113x; 1.2113x over previous
//
#include <hip/hip_runtime.h>
#include <math.h>

#define T_SEQ   1000
#define BATCH   8
#define DMODEL  512
#define NHEAD   8
#define DHEAD   64
#define FFDIM   2048
#define NLAYER  4
#define MROWS   (BATCH * T_SEQ)   // 8000
#define TCHUNK  25
#define QKS     1024              // Q|K row stride (elements)
#define VTS     1024              // Vt row stride (elements, padded from 1000)

typedef __bf16 bf16x8 __attribute__((ext_vector_type(8)));
typedef __bf16 bf16x4 __attribute__((ext_vector_type(4)));
typedef float  f32x4  __attribute__((ext_vector_type(4)));
typedef float  f32x16 __attribute__((ext_vector_type(16)));

#define GL2LDS(g, l) \
    __builtin_amdgcn_global_load_lds((const __attribute__((address_space(1))) void*)(g), \
                                     (__attribute__((address_space(3))) void*)(l), 16, 0, 0)

// ---------------------------------------------------------------------------
__global__ __launch_bounds__(256)
void f2bf(const float* __restrict__ in, __bf16* __restrict__ out)
{
    int i = (blockIdx.x * 256 + threadIdx.x) * 4;
    float4 v = *(const float4*)(in + i);
    bf16x4 o;
    o[0] = (__bf16)v.x; o[1] = (__bf16)v.y; o[2] = (__bf16)v.z; o[3] = (__bf16)v.w;
    *(bf16x4*)(out + i) = o;
}

// ---------------------------------------------------------------------------
// bf16 MFMA GEMM: C(MxN) = A(MxK) @ B(NxK)^T + bias.   M % 64 == 0.
// 64x128 tile, BK=64, 4 waves (2x2), 16x16x32 MFMA — R10 proven config:
// T2 both-sides swizzle, T4 3-buffer counted vmcnt(6), T5 setprio,
// T1 bijective XCD swizzle (consecutive work-ids share the A row-band).
// MODE 0: bf16 row-major out (stride N), optional RELU.
// MODE 1: + fused sinusoidal PE (embed; N == DMODEL).
// MODE 2: QKV split — QK blocks (col0<1024) -> qkb[gr*QKS+gc];
//         V blocks (col0>=1024) -> LDS-staged TRANSPOSED store to Vt
//         (fixes the 2B-scatter store-transaction bottleneck).
// ---------------------------------------------------------------------------
template<int MODE, bool RELU>
__global__ __launch_bounds__(256)
void gemm_bf16(const __bf16* __restrict__ A, const __bf16* __restrict__ B,
               const float* __restrict__ bias, __bf16* __restrict__ Cb,
               __bf16* __restrict__ Vt, int M, int N, int K)
{
    __shared__ __align__(16) __bf16 As[3][64 * 64];    // 3 x 8 KB
    __shared__ __align__(16) __bf16 Bs[3][128 * 64];   // 3 x 16 KB (V-epilogue overlay)

    const int tid  = threadIdx.x;
    const int lane = tid & 63;
    const int w    = tid >> 6;
    const int wr   = w >> 1, wc = w & 1;

    // T1: bijective XCD swizzle (m204)
    const int gx  = gridDim.x;
    const int nwg = gx * gridDim.y;
    const int bid = blockIdx.y * gx + blockIdx.x;
    const int qc  = nwg >> 3, rc = nwg & 7;
    const int xcd = bid & 7, idx = bid >> 3;
    const int swz = (xcd < rc) ? xcd * (qc + 1) + idx
                               : rc * (qc + 1) + (xcd - rc) * qc + idx;
    const int row0 = (swz / gx) * 64;
    const int col0 = (swz % gx) * 128;

    size_t aoffg[2], boffg[4];
    int    ldso[4];
    #pragma unroll
    for (int p = 0; p < 4; ++p) {
        const int bo = p * 4096 + tid * 16;
        const int r  = bo >> 7;
        const int cs = (bo & 127) ^ ((r & 7) << 4);
        if (p < 2) aoffg[p] = (size_t)(row0 + r) * K * 2 + cs;
        boffg[p] = (size_t)(col0 + r) * K * 2 + cs;
        ldso[p]  = bo;
    }

    f32x4 acc[2][4];
    #pragma unroll
    for (int m = 0; m < 2; ++m)
        #pragma unroll
        for (int n = 0; n < 4; ++n) acc[m][n] = (f32x4)0.f;

    const char* gA = (const char*)A;
    const char* gB = (const char*)B;
    const int nt = K >> 6;

    auto STAGE = [&](int tt, int buf) {
        const size_t kb = (size_t)tt << 7;
        char* lA = (char*)As[buf];
        char* lB = (char*)Bs[buf];
        #pragma unroll
        for (int p = 0; p < 2; ++p) GL2LDS(gA + aoffg[p] + kb, lA + ldso[p]);
        #pragma unroll
        for (int p = 0; p < 4; ++p) GL2LDS(gB + boffg[p] + kb, lB + ldso[p]);
    };

    STAGE(0, 0);
    STAGE(1, 1);
    asm volatile("s_waitcnt vmcnt(6)" ::: "memory");
    __builtin_amdgcn_s_barrier();
    __builtin_amdgcn_sched_barrier(0);

    int bc = 0, bn = 2;
    for (int t = 0; t < nt; ++t) {
        if (t + 2 < nt) STAGE(t + 2, bn);
        const char* as = (const char*)As[bc];
        const char* bs = (const char*)Bs[bc];
        __builtin_amdgcn_s_setprio(1);
        #pragma unroll
        for (int ks = 0; ks < 2; ++ks) {
            bf16x8 af[2], bfr[4];
            const int cb = ks * 64 + (lane >> 4) * 16;
            #pragma unroll
            for (int m = 0; m < 2; ++m) {
                const int rr = wr * 32 + m * 16 + (lane & 15);
                af[m] = *(const bf16x8*)(as + rr * 128 + (cb ^ ((rr & 7) << 4)));
            }
            #pragma unroll
            for (int n = 0; n < 4; ++n) {
                const int rr = wc * 64 + n * 16 + (lane & 15);
                bfr[n] = *(const bf16x8*)(bs + rr * 128 + (cb ^ ((rr & 7) << 4)));
            }
            #pragma unroll
            for (int m = 0; m < 2; ++m)
                #pragma unroll
                for (int n = 0; n < 4; ++n)
                    acc[m][n] = __builtin_amdgcn_mfma_f32_16x16x32_bf16(af[m], bfr[n], acc[m][n], 0, 0, 0);
        }
        __builtin_amdgcn_s_setprio(0);
        if (t + 2 < nt) { asm volatile("s_waitcnt vmcnt(6)" ::: "memory"); }
        else            { asm volatile("s_waitcnt vmcnt(0)" ::: "memory"); }
        __builtin_amdgcn_s_barrier();
        __builtin_amdgcn_sched_barrier(0);
        bc = bc + 1; if (bc == 3) bc = 0;
        bn = bn + 1; if (bn == 3) bn = 0;
    }

    const int crow = (lane >> 4) * 4;
    const int ccol = lane & 15;

    if (MODE == 2 && col0 >= 1024) {
        // ---- V block: stage [128 d][68] transposed tile in LDS, then
        //      coalesced 16B-per-lane stores (128B contiguous per 8 lanes) ----
        __bf16* vtl = &Bs[0][0];                     // 128*68 = 17408 B overlay
        #pragma unroll
        for (int n = 0; n < 4; ++n) {
            const int dl = wc * 64 + n * 16 + ccol;
            const float bv = bias[col0 + dl];
            #pragma unroll
            for (int m = 0; m < 2; ++m) {
                const int tl0 = wr * 32 + m * 16 + crow;
                #pragma unroll
                for (int r = 0; r < 4; ++r)
                    vtl[dl * 68 + tl0 + r] = (__bf16)(acc[m][n][r] + bv);
            }
        }
        __syncthreads();
        const int dbase = col0 - 1024;
        #pragma unroll
        for (int pass = 0; pass < 4; ++pass) {
            const int dl = pass * 32 + (tid >> 3);
            const int tc = (tid & 7) * 8;
            const int gr = row0 + tc;
            const bf16x8 vv = *(const bf16x8*)(vtl + dl * 68 + tc);
            const int bidx = gr / T_SEQ;
            const int tt   = gr - bidx * T_SEQ;
            __bf16* dst = Vt + (((size_t)(bidx * DMODEL + dbase + dl)) << 10) + tt;
            if (tt + 8 <= T_SEQ) {
                *(bf16x8*)dst = vv;
            } else {
                #pragma unroll
                for (int e = 0; e < 8; ++e) {
                    const int gre = gr + e;
                    const int be = gre / T_SEQ, te = gre - be * T_SEQ;
                    Vt[(((size_t)(be * DMODEL + dbase + dl)) << 10) + te] = vv[e];
                }
            }
        }
        return;
    }

    #pragma unroll
    for (int n = 0; n < 4; ++n) {
        const int gc = col0 + wc * 64 + n * 16 + ccol;
        const float bv = bias[gc];
        float freq = 0.f;
        if (MODE == 1) freq = __expf((float)(gc & ~1) * (-9.210340371976184f / (float)DMODEL));
        #pragma unroll
        for (int m = 0; m < 2; ++m) {
            const int gr0 = row0 + wr * 32 + m * 16 + crow;
            #pragma unroll
            for (int r = 0; r < 4; ++r) {
                const int gr = gr0 + r;
                float v = acc[m][n][r] + bv;
                if (MODE == 1) {
                    const int tt = gr % T_SEQ;
                    const float ang = (float)tt * freq;
                    v += (gc & 1) ? __cosf(ang) : __sinf(ang);
                }
                if (RELU) v = fmaxf(v, 0.f);
                if (MODE == 2) {
                    Cb[(size_t)gr * QKS + gc] = (__bf16)v;   // QK block
                } else {
                    Cb[(size_t)gr * N + gc] = (__bf16)v;
                }
            }
        }
    }
}

// ---------------------------------------------------------------------------
// MFMA flash attention v2.1: one WAVE per block (64 thr, 1024 blocks);
// head pair (ph, 7-ph) per wave => constant work. QK^T swapped (col=q);
// PV computes O^T = mfma(V^T-frag, P^T-frag) from transposed Vt.
// ---------------------------------------------------------------------------
__global__ __launch_bounds__(64)
void attn_mfma(const __bf16* __restrict__ qkb, const __bf16* __restrict__ vt,
               __bf16* __restrict__ o)
{
    const int wv   = blockIdx.x;
    const int lane = threadIdx.x;
    const int ph   = wv & 3;
    const int qt   = (wv >> 2) & 31;
    const int b    = wv >> 7;
    const int qb   = qt * 32;
    const int half = lane >> 5;
    const int ql   = lane & 31;
    const int i    = qb + ql;
    const int iq   = (i < T_SEQ) ? i : (T_SEQ - 1);
    const float C2 = 0.125f * 1.44269504089f;

    const __bf16* QKb = qkb + (size_t)b * T_SEQ * QKS;

    #pragma unroll
    for (int jb = 0; jb < 2; ++jb) {
        const int hh = jb ? (7 - ph) : ph;
        const __bf16* Q = QKb + hh * DHEAD;
        const __bf16* K = Q + 512;
        const __bf16* Vb = vt + (((size_t)b * DMODEL + hh * DHEAD) << 10);

        bf16x8 qf[4];
        {
            const __bf16* qrow = Q + (size_t)iq * QKS + half * 8;
            #pragma unroll
            for (int ds = 0; ds < 4; ++ds)
                qf[ds] = *(const bf16x8*)(qrow + ds * 16);
        }

        const int w = 25 * (hh + 1);
        const int kb_lo = (qb - w > 0 ? qb - w : 0) & ~31;
        const int kb_hi = (qb + 31 + w < T_SEQ - 1) ? (qb + 31 + w) : (T_SEQ - 1);
        const int spanv = (2 * w < T_SEQ - 1 - i + w) ? 2 * w : (T_SEQ - 1 - i + w);
        const unsigned span = (unsigned)spanv;

        float m2 = -1e9f, l = 0.f;
        f32x16 oa0 = (f32x16)0.f, oa1 = (f32x16)0.f;

        for (int kb = kb_lo; kb <= kb_hi; kb += 32) {
            f32x16 sv = (f32x16)0.f;
            {
                int krow = kb + ql; if (krow > T_SEQ - 1) krow = T_SEQ - 1;
                const __bf16* kr = K + (size_t)krow * QKS + half * 8;
                #pragma unroll
                for (int ds = 0; ds < 4; ++ds) {
                    bf16x8 kf = *(const bf16x8*)(kr + ds * 16);
                    sv = __builtin_amdgcn_mfma_f32_32x32x16_bf16(kf, qf[ds], sv, 0, 0, 0);
                }
            }

            const bool full = (kb >= qb + 31 - w) && (kb + 31 <= qb + w)
                           && (kb + 31 <= T_SEQ - 1);
            float s2[16];
            if (full) {
                #pragma unroll
                for (int r = 0; r < 16; ++r) s2[r] = sv[r] * C2;
            } else {
                const int base = kb - i + w;
                #pragma unroll
                for (int r = 0; r < 16; ++r) {
                    const int kr = (r & 3) + 8 * (r >> 2) + 4 * half;
                    const unsigned jrel = (unsigned)(base + kr);
                    s2[r] = (jrel <= span) ? sv[r] * C2 : -1e9f;
                }
            }

            float mx = s2[0];
            #pragma unroll
            for (int r = 1; r < 16; ++r) mx = fmaxf(mx, s2[r]);
            mx = fmaxf(mx, __shfl_xor(mx, 32, 64));

            if (!__all(mx <= m2 + 8.0f)) {
                const float mnew  = fmaxf(m2, mx);
                const float scale = exp2f(m2 - mnew);
                m2 = mnew;
                l *= scale;
                oa0 *= scale;
                oa1 *= scale;
            }

            float p[16];
            float ps = 0.f;
            #pragma unroll
            for (int r = 0; r < 16; ++r) { p[r] = exp2f(s2[r] - m2); ps += p[r]; }
            ps += __shfl_xor(ps, 32, 64);
            l += ps;

            unsigned pk[8];
            #pragma unroll
            for (int t = 0; t < 8; ++t) {
                union { unsigned u; __bf16 h[2]; } cv;
                cv.h[0] = (__bf16)p[2 * t];
                cv.h[1] = (__bf16)p[2 * t + 1];
                pk[t] = cv.u;
            }
            unsigned y[8];
            #pragma unroll
            for (int t = 0; t < 8; ++t)
                y[t] = (unsigned)__shfl_xor((int)pk[t], 32, 64);

            union { unsigned u[4]; bf16x8 v; } pa0, pa1;
            if (half == 0) {
                pa0.u[0] = pk[0]; pa0.u[1] = pk[1]; pa0.u[2] = y[0];  pa0.u[3] = y[1];
                pa1.u[0] = pk[4]; pa1.u[1] = pk[5]; pa1.u[2] = y[4];  pa1.u[3] = y[5];
            } else {
                pa0.u[0] = y[2];  pa0.u[1] = y[3];  pa0.u[2] = pk[2]; pa0.u[3] = pk[3];
                pa1.u[0] = y[6];  pa1.u[1] = y[7];  pa1.u[2] = pk[6]; pa1.u[3] = pk[7];
            }

            #pragma unroll
            for (int ks = 0; ks < 2; ++ks) {
                const int kc = kb + ks * 16 + half * 8;
                #pragma unroll
                for (int dh = 0; dh < 2; ++dh) {
                    const bf16x8 vf = *(const bf16x8*)(Vb + (((size_t)(dh * 32 + ql)) << 10) + kc);
                    if (dh == 0)
                        oa0 = __builtin_amdgcn_mfma_f32_32x32x16_bf16(vf, ks ? pa1.v : pa0.v, oa0, 0, 0, 0);
                    else
                        oa1 = __builtin_amdgcn_mfma_f32_32x32x16_bf16(vf, ks ? pa1.v : pa0.v, oa1, 0, 0, 0);
                }
            }
        }

        if (i < T_SEQ) {
            const float ri = 1.f / l;
            __bf16* orow = o + (size_t)(b * T_SEQ + i) * DMODEL + hh * DHEAD;
            #pragma unroll
            for (int g = 0; g < 4; ++g) {
                bf16x4 v0, v1;
                #pragma unroll
                for (int r = 0; r < 4; ++r) {
                    v0[r] = (__bf16)(oa0[g * 4 + r] * ri);
                    v1[r] = (__bf16)(oa1[g * 4 + r] * ri);
                }
                *(bf16x4*)(orow + g * 8 + half * 4)      = v0;
                *(bf16x4*)(orow + 32 + g * 8 + half * 4) = v1;
            }
        }
    }
}

// ---------------------------------------------------------------------------
// h = LayerNorm(h + t) * g + b — bf16 residual stream, fp32 math.
// ---------------------------------------------------------------------------
__global__ __launch_bounds__(256)
void add_ln(__bf16* __restrict__ hb, const __bf16* __restrict__ tbuf,
            const float* __restrict__ g, const float* __restrict__ b)
{
    const int row  = blockIdx.x * 4 + (threadIdx.x >> 6);
    const int lane = threadIdx.x & 63;
    __bf16*       hp = hb   + (size_t)row * DMODEL + lane * 8;
    const __bf16* tp = tbuf + (size_t)row * DMODEL + lane * 8;

    bf16x8 hv = *(const bf16x8*)hp;
    bf16x8 tv = *(const bf16x8*)tp;
    float xv[8];
    #pragma unroll
    for (int j = 0; j < 8; ++j) xv[j] = (float)hv[j] + (float)tv[j];

    float s = 0.f;
    #pragma unroll
    for (int j = 0; j < 8; ++j) s += xv[j];
    #pragma unroll
    for (int off = 32; off >= 1; off >>= 1) s += __shfl_xor(s, off, 64);
    float mean = s * (1.f / DMODEL);

    float vs = 0.f;
    #pragma unroll
    for (int j = 0; j < 8; ++j) { float d = xv[j] - mean; vs += d * d; }
    #pragma unroll
    for (int off = 32; off >= 1; off >>= 1) vs += __shfl_xor(vs, off, 64);
    float rstd = rsqrtf(vs * (1.f / DMODEL) + 1e-5f);

    float4 g0 = *(const float4*)(g + lane * 8);
    float4 g1 = *(const float4*)(g + lane * 8 + 4);
    float4 b0 = *(const float4*)(b + lane * 8);
    float4 b1 = *(const float4*)(b + lane * 8 + 4);
    float gg[8] = {g0.x, g0.y, g0.z, g0.w, g1.x, g1.y, g1.z, g1.w};
    float bb[8] = {b0.x, b0.y, b0.z, b0.w, b1.x, b1.y, b1.z, b1.w};

    bf16x8 ob;
    #pragma unroll
    for (int j = 0; j < 8; ++j)
        ob[j] = (__bf16)((xv[j] - mean) * rstd * gg[j] + bb[j]);
    *(bf16x8*)hp = ob;
}

// ---------------------------------------------------------------------------
__global__ __launch_bounds__(256)
void pool_p1(const __bf16* __restrict__ hb, float* __restrict__ part)
{
    const int bb  = blockIdx.x;
    const int tc  = blockIdx.y;
    const int tid = threadIdx.x;
    const int t0  = tc * (T_SEQ / TCHUNK);
    const __bf16* p = hb + ((size_t)bb * T_SEQ + t0) * DMODEL;

    float mx0 = -3.4e38f, mx1 = -3.4e38f;
    for (int t = 0; t < T_SEQ / TCHUNK; ++t) {
        mx0 = fmaxf(mx0, (float)p[(size_t)t * DMODEL + tid]);
        mx1 = fmaxf(mx1, (float)p[(size_t)t * DMODEL + 256 + tid]);
    }
    float* q = part + ((size_t)bb * TCHUNK + tc) * DMODEL;
    q[tid]       = mx0;
    q[tid + 256] = mx1;
}

// ---------------------------------------------------------------------------
__global__ __launch_bounds__(256)
void pool_p2(const float* __restrict__ part, const float* __restrict__ Wcls,
             const float* __restrict__ bcls, float* __restrict__ out)
{
    __shared__ float pooled[DMODEL];
    __shared__ float logits[8];
    const int bb  = blockIdx.x;
    const int tid = threadIdx.x;

    const float* q = part + (size_t)bb * TCHUNK * DMODEL;
    #pragma unroll
    for (int u = 0; u < 2; ++u) {
        const int d = tid + u * 256;
        float mx = -3.4e38f;
        for (int c = 0; c < TCHUNK; ++c) mx = fmaxf(mx, q[(size_t)c * DMODEL + d]);
        pooled[d] = mx;
    }
    __syncthreads();

    const int cls  = tid >> 5;
    const int lsub = tid & 31;
    const float* wr = Wcls + cls * DMODEL;
    float s = 0.f;
    #pragma unroll
    for (int u = 0; u < 16; ++u) {
        const int d = lsub + u * 32;
        s = fmaf(pooled[d], wr[d], s);
    }
    #pragma unroll
    for (int off = 16; off >= 1; off >>= 1) s += __shfl_xor(s, off, 32);
    if (lsub == 0) logits[cls] = s + bcls[cls];
    __syncthreads();

    if (tid == 0) {
        float mx = logits[0];
        for (int c = 1; c < 8; ++c) mx = fmaxf(mx, logits[c]);
        float se = 0.f;
        for (int c = 0; c < 8; ++c) se += expf(logits[c] - mx);
        float lse = logf(se) + mx;
        for (int c = 0; c < 8; ++c) out[bb * 8 + c] = logits[c] - lse;
    }
}

// ---------------------------------------------------------------------------
extern "C" void kernel_launch(void* const* d_in, const int* in_sizes, int n_in,
                              void* d_out, int out_size, void* d_ws, size_t ws_size,
                              hipStream_t stream)
{
    const float* x    = (const float*)d_in[0];
    const float* Wemb = (const float*)d_in[1];
    const float* bemb = (const float*)d_in[2];
    const float* Wqkv = (const float*)d_in[3];
    const float* bqkv = (const float*)d_in[4];
    const float* Wo   = (const float*)d_in[5];
    const float* bo   = (const float*)d_in[6];
    const float* W1   = (const float*)d_in[7];
    const float* b1f  = (const float*)d_in[8];
    const float* W2   = (const float*)d_in[9];
    const float* b2f  = (const float*)d_in[10];
    const float* g1   = (const float*)d_in[11];
    const float* be1  = (const float*)d_in[12];
    const float* g2   = (const float*)d_in[13];
    const float* be2  = (const float*)d_in[14];
    const float* Wcls = (const float*)d_in[15];
    const float* bcls = (const float*)d_in[16];
    float* out = (float*)d_out;

    // -------- workspace layout (all bf16 except pool partials) --------
    __bf16* hb   = (__bf16*)d_ws;                      // 8000x512
    __bf16* qkb  = hb   + (size_t)MROWS * DMODEL;      // 8000x1024 (Q|K)
    __bf16* vtb  = qkb  + (size_t)MROWS * QKS;         // 8x512x1024 transposed V
    __bf16* attb = vtb  + (size_t)BATCH * DMODEL * VTS;// 8000x512
    __bf16* ff1b = attb + (size_t)MROWS * DMODEL;      // 8000x2048
    __bf16* tmpB = ff1b + (size_t)MROWS * FFDIM;       // 8000x512
    __bf16* xb   = tmpB + (size_t)MROWS * DMODEL;      // 8000x256
    __bf16* wEmb = xb   + (size_t)MROWS * 256;
    __bf16* wQKV = wEmb + 512 * 256;
    __bf16* wWo  = wQKV + (size_t)NLAYER * 3 * DMODEL * DMODEL;
    __bf16* wW1  = wWo  + (size_t)NLAYER * DMODEL * DMODEL;
    __bf16* wW2  = wW1  + (size_t)NLAYER * FFDIM * DMODEL;
    float*  partF = (float*)(wW2 + (size_t)NLAYER * DMODEL * FFDIM); // 8x25x512

    dim3 blk(256);

    f2bf<<<dim3(MROWS * 256 / 1024), blk, 0, stream>>>(x, xb);
    f2bf<<<dim3(512 * 256 / 1024), blk, 0, stream>>>(Wemb, wEmb);
    f2bf<<<dim3(NLAYER * 3 * DMODEL * DMODEL / 1024), blk, 0, stream>>>(Wqkv, wQKV);
    f2bf<<<dim3(NLAYER * DMODEL * DMODEL / 1024), blk, 0, stream>>>(Wo, wWo);
    f2bf<<<dim3(NLAYER * FFDIM * DMODEL / 1024), blk, 0, stream>>>(W1, wW1);
    f2bf<<<dim3(NLAYER * DMODEL * FFDIM / 1024), blk, 0, stream>>>(W2, wW2);

    // embed + fused PE -> hb
    gemm_bf16<1, false><<<dim3(4, 125), blk, 0, stream>>>(
        xb, wEmb, bemb, hb, nullptr, MROWS, DMODEL, 256);

    for (int l = 0; l < NLAYER; ++l) {
        gemm_bf16<2, false><<<dim3(12, 125), blk, 0, stream>>>(
            hb, wQKV + (size_t)l * 3 * DMODEL * DMODEL, bqkv + (size_t)l * 3 * DMODEL,
            qkb, vtb, MROWS, 3 * DMODEL, DMODEL);
        attn_mfma<<<dim3(1024), dim3(64), 0, stream>>>(qkb, vtb, attb);
        gemm_bf16<0, false><<<dim3(4, 125), blk, 0, stream>>>(
            attb, wWo + (size_t)l * DMODEL * DMODEL, bo + (size_t)l * DMODEL,
            tmpB, nullptr, MROWS, DMODEL, DMODEL);
        add_ln<<<dim3(MROWS / 4), blk, 0, stream>>>(
            hb, tmpB, g1 + (size_t)l * DMODEL, be1 + (size_t)l * DMODEL);
        gemm_bf16<0, true><<<dim3(16, 125), blk, 0, stream>>>(
            hb, wW1 + (size_t)l * FFDIM * DMODEL, b1f + (size_t)l * FFDIM,
            ff1b, nullptr, MROWS, FFDIM, DMODEL);
        gemm_bf16<0, false><<<dim3(4, 125), blk, 0, stream>>>(
            ff1b, wW2 + (size_t)l * DMODEL * FFDIM, b2f + (size_t)l * DMODEL,
            tmpB, nullptr, MROWS, DMODEL, FFDIM);
        add_ln<<<dim3(MROWS / 4), blk, 0, stream>>>(
            hb, tmpB, g2 + (size_t)l * DMODEL, be2 + (size_t)l * DMODEL);
    }

    pool_p1<<<dim3(BATCH, TCHUNK), blk, 0, stream>>>(hb, partF);
    pool_p2<<<dim3(BATCH), blk, 0, stream>>>(partF, Wcls, bcls, out);
}

// Round 14
// 599.785 us; speedup vs baseline: 1.2201x; 1.0072x over previous
//
#include <hip/hip_runtime.h>
#include <math.h>

#define T_SEQ   1000
#define BATCH   8
#define DMODEL  512
#define NHEAD   8
#define DHEAD   64
#define FFDIM   2048
#define NLAYER  4
#define MROWS   (BATCH * T_SEQ)   // 8000
#define TCHUNK  25
#define QKS     1024              // Q|K row stride (elements)
#define VTS     1024              // Vt row stride (elements, padded from 1000)

typedef __bf16 bf16x8 __attribute__((ext_vector_type(8)));
typedef __bf16 bf16x4 __attribute__((ext_vector_type(4)));
typedef float  f32x4  __attribute__((ext_vector_type(4)));
typedef float  f32x16 __attribute__((ext_vector_type(16)));

#define GL2LDS(g, l) \
    __builtin_amdgcn_global_load_lds((const __attribute__((address_space(1))) void*)(g), \
                                     (__attribute__((address_space(3))) void*)(l), 16, 0, 0)

// ---------------------------------------------------------------------------
// fp32 -> bf16 for all 6 arrays in ONE launch. Each block converts 1024
// elems. Segment selection via monotone prefix-sum scan (R13 bug fixed:
// the old scan could re-trigger on later segments after the first miss).
// ---------------------------------------------------------------------------
struct F2BFArgs {
    const float* src[6];
    __bf16*      dst[6];
    int          off[7];    // prefix sums: off[s] = first block of segment s
};

__global__ __launch_bounds__(256)
void f2bf_all(F2BFArgs a)
{
    const int blk = blockIdx.x;
    int seg = 0;
    #pragma unroll
    for (int s = 1; s < 6; ++s)
        if (blk >= a.off[s]) seg = s;
    const int i = (blk - a.off[seg]) * 1024 + threadIdx.x * 4;
    float4 v = *(const float4*)(a.src[seg] + i);
    bf16x4 o;
    o[0] = (__bf16)v.x; o[1] = (__bf16)v.y; o[2] = (__bf16)v.z; o[3] = (__bf16)v.w;
    *(bf16x4*)(a.dst[seg] + i) = o;
}

// ---------------------------------------------------------------------------
// bf16 MFMA GEMM: C(MxN) = A(MxK) @ B(NxK)^T + bias.   M % 64 == 0.
// 64x128 tile, BK=64, 4 waves (2x2), 16x16x32 MFMA — R10/R12 proven config:
// T2 both-sides swizzle, T4 3-buffer counted vmcnt(6), T5 setprio,
// T1 bijective XCD swizzle (consecutive work-ids share the A row-band).
// MODE 0: bf16 row-major out (stride N), optional RELU.
// MODE 1: + fused sinusoidal PE (embed; N == DMODEL).
// MODE 2: QKV split — QK blocks (col0<1024) -> qkb[gr*QKS+gc];
//         V blocks (col0>=1024) -> LDS-staged TRANSPOSED store to Vt.
// ---------------------------------------------------------------------------
template<int MODE, bool RELU>
__global__ __launch_bounds__(256)
void gemm_bf16(const __bf16* __restrict__ A, const __bf16* __restrict__ B,
               const float* __restrict__ bias, __bf16* __restrict__ Cb,
               __bf16* __restrict__ Vt, int M, int N, int K)
{
    __shared__ __align__(16) __bf16 As[3][64 * 64];    // 3 x 8 KB
    __shared__ __align__(16) __bf16 Bs[3][128 * 64];   // 3 x 16 KB (V-epilogue overlay)

    const int tid  = threadIdx.x;
    const int lane = tid & 63;
    const int w    = tid >> 6;
    const int wr   = w >> 1, wc = w & 1;

    // T1: bijective XCD swizzle (m204)
    const int gx  = gridDim.x;
    const int nwg = gx * gridDim.y;
    const int bid = blockIdx.y * gx + blockIdx.x;
    const int qc  = nwg >> 3, rc = nwg & 7;
    const int xcd = bid & 7, idx = bid >> 3;
    const int swz = (xcd < rc) ? xcd * (qc + 1) + idx
                               : rc * (qc + 1) + (xcd - rc) * qc + idx;
    const int row0 = (swz / gx) * 64;
    const int col0 = (swz % gx) * 128;

    size_t aoffg[2], boffg[4];
    int    ldso[4];
    #pragma unroll
    for (int p = 0; p < 4; ++p) {
        const int bo = p * 4096 + tid * 16;
        const int r  = bo >> 7;
        const int cs = (bo & 127) ^ ((r & 7) << 4);
        if (p < 2) aoffg[p] = (size_t)(row0 + r) * K * 2 + cs;
        boffg[p] = (size_t)(col0 + r) * K * 2 + cs;
        ldso[p]  = bo;
    }

    f32x4 acc[2][4];
    #pragma unroll
    for (int m = 0; m < 2; ++m)
        #pragma unroll
        for (int n = 0; n < 4; ++n) acc[m][n] = (f32x4)0.f;

    const char* gA = (const char*)A;
    const char* gB = (const char*)B;
    const int nt = K >> 6;

    auto STAGE = [&](int tt, int buf) {
        const size_t kb = (size_t)tt << 7;
        char* lA = (char*)As[buf];
        char* lB = (char*)Bs[buf];
        #pragma unroll
        for (int p = 0; p < 2; ++p) GL2LDS(gA + aoffg[p] + kb, lA + ldso[p]);
        #pragma unroll
        for (int p = 0; p < 4; ++p) GL2LDS(gB + boffg[p] + kb, lB + ldso[p]);
    };

    STAGE(0, 0);
    STAGE(1, 1);
    asm volatile("s_waitcnt vmcnt(6)" ::: "memory");
    __builtin_amdgcn_s_barrier();
    __builtin_amdgcn_sched_barrier(0);

    int bc = 0, bn = 2;
    for (int t = 0; t < nt; ++t) {
        if (t + 2 < nt) STAGE(t + 2, bn);
        const char* as = (const char*)As[bc];
        const char* bs = (const char*)Bs[bc];
        __builtin_amdgcn_s_setprio(1);
        #pragma unroll
        for (int ks = 0; ks < 2; ++ks) {
            bf16x8 af[2], bfr[4];
            const int cb = ks * 64 + (lane >> 4) * 16;
            #pragma unroll
            for (int m = 0; m < 2; ++m) {
                const int rr = wr * 32 + m * 16 + (lane & 15);
                af[m] = *(const bf16x8*)(as + rr * 128 + (cb ^ ((rr & 7) << 4)));
            }
            #pragma unroll
            for (int n = 0; n < 4; ++n) {
                const int rr = wc * 64 + n * 16 + (lane & 15);
                bfr[n] = *(const bf16x8*)(bs + rr * 128 + (cb ^ ((rr & 7) << 4)));
            }
            #pragma unroll
            for (int m = 0; m < 2; ++m)
                #pragma unroll
                for (int n = 0; n < 4; ++n)
                    acc[m][n] = __builtin_amdgcn_mfma_f32_16x16x32_bf16(af[m], bfr[n], acc[m][n], 0, 0, 0);
        }
        __builtin_amdgcn_s_setprio(0);
        if (t + 2 < nt) { asm volatile("s_waitcnt vmcnt(6)" ::: "memory"); }
        else            { asm volatile("s_waitcnt vmcnt(0)" ::: "memory"); }
        __builtin_amdgcn_s_barrier();
        __builtin_amdgcn_sched_barrier(0);
        bc = bc + 1; if (bc == 3) bc = 0;
        bn = bn + 1; if (bn == 3) bn = 0;
    }

    const int crow = (lane >> 4) * 4;
    const int ccol = lane & 15;

    if (MODE == 2 && col0 >= 1024) {
        // V block: stage [128 d][68] transposed tile in LDS, then coalesced
        // 16B-per-lane stores (fixes the 2B-scatter transaction bottleneck).
        __bf16* vtl = &Bs[0][0];                     // 128*68 = 17408 B overlay
        #pragma unroll
        for (int n = 0; n < 4; ++n) {
            const int dl = wc * 64 + n * 16 + ccol;
            const float bv = bias[col0 + dl];
            #pragma unroll
            for (int m = 0; m < 2; ++m) {
                const int tl0 = wr * 32 + m * 16 + crow;
                #pragma unroll
                for (int r = 0; r < 4; ++r)
                    vtl[dl * 68 + tl0 + r] = (__bf16)(acc[m][n][r] + bv);
            }
        }
        __syncthreads();
        const int dbase = col0 - 1024;
        #pragma unroll
        for (int pass = 0; pass < 4; ++pass) {
            const int dl = pass * 32 + (tid >> 3);
            const int tc = (tid & 7) * 8;
            const int gr = row0 + tc;
            const bf16x8 vv = *(const bf16x8*)(vtl + dl * 68 + tc);
            const int bidx = gr / T_SEQ;
            const int tt   = gr - bidx * T_SEQ;
            __bf16* dst = Vt + (((size_t)(bidx * DMODEL + dbase + dl)) << 10) + tt;
            if (tt + 8 <= T_SEQ) {
                *(bf16x8*)dst = vv;
            } else {
                #pragma unroll
                for (int e = 0; e < 8; ++e) {
                    const int gre = gr + e;
                    const int be = gre / T_SEQ, te = gre - be * T_SEQ;
                    Vt[(((size_t)(be * DMODEL + dbase + dl)) << 10) + te] = vv[e];
                }
            }
        }
        return;
    }

    #pragma unroll
    for (int n = 0; n < 4; ++n) {
        const int gc = col0 + wc * 64 + n * 16 + ccol;
        const float bv = bias[gc];
        float freq = 0.f;
        if (MODE == 1) freq = __expf((float)(gc & ~1) * (-9.210340371976184f / (float)DMODEL));
        #pragma unroll
        for (int m = 0; m < 2; ++m) {
            const int gr0 = row0 + wr * 32 + m * 16 + crow;
            #pragma unroll
            for (int r = 0; r < 4; ++r) {
                const int gr = gr0 + r;
                float v = acc[m][n][r] + bv;
                if (MODE == 1) {
                    const int tt = gr % T_SEQ;
                    const float ang = (float)tt * freq;
                    v += (gc & 1) ? __cosf(ang) : __sinf(ang);
                }
                if (RELU) v = fmaxf(v, 0.f);
                if (MODE == 2) {
                    Cb[(size_t)gr * QKS + gc] = (__bf16)v;   // QK block
                } else {
                    Cb[(size_t)gr * N + gc] = (__bf16)v;
                }
            }
        }
    }
}

// ---------------------------------------------------------------------------
// MFMA flash attention v3: 2048 single-wave blocks (2 waves/SIMD), job =
// (b, qt, head) with head = blockIdx & 7 — any 8 consecutive block ids span
// all heads, so every CU gets the same head mix (balanced without pairing).
// QK^T swapped (col=q); PV computes O^T = mfma(V^T-frag, P^T-frag).
// ---------------------------------------------------------------------------
__global__ __launch_bounds__(64)
void attn_mfma(const __bf16* __restrict__ qkb, const __bf16* __restrict__ vt,
               __bf16* __restrict__ o)
{
    const int wv   = blockIdx.x;
    const int lane = threadIdx.x;
    const int hh   = wv & 7;
    const int qt   = (wv >> 3) & 31;
    const int b    = wv >> 8;
    const int qb   = qt * 32;
    const int half = lane >> 5;
    const int ql   = lane & 31;
    const int i    = qb + ql;
    const int iq   = (i < T_SEQ) ? i : (T_SEQ - 1);
    const float C2 = 0.125f * 1.44269504089f;

    const __bf16* Q = qkb + (size_t)b * T_SEQ * QKS + hh * DHEAD;
    const __bf16* K = Q + 512;
    const __bf16* Vb = vt + (((size_t)b * DMODEL + hh * DHEAD) << 10);

    bf16x8 qf[4];
    {
        const __bf16* qrow = Q + (size_t)iq * QKS + half * 8;
        #pragma unroll
        for (int ds = 0; ds < 4; ++ds)
            qf[ds] = *(const bf16x8*)(qrow + ds * 16);
    }

    const int w = 25 * (hh + 1);
    const int kb_lo = (qb - w > 0 ? qb - w : 0) & ~31;
    const int kb_hi = (qb + 31 + w < T_SEQ - 1) ? (qb + 31 + w) : (T_SEQ - 1);
    const int spanv = (2 * w < T_SEQ - 1 - i + w) ? 2 * w : (T_SEQ - 1 - i + w);
    const unsigned span = (unsigned)spanv;

    float m2 = -1e9f, l = 0.f;
    f32x16 oa0 = (f32x16)0.f, oa1 = (f32x16)0.f;

    for (int kb = kb_lo; kb <= kb_hi; kb += 32) {
        f32x16 sv = (f32x16)0.f;
        {
            int krow = kb + ql; if (krow > T_SEQ - 1) krow = T_SEQ - 1;
            const __bf16* kr = K + (size_t)krow * QKS + half * 8;
            #pragma unroll
            for (int ds = 0; ds < 4; ++ds) {
                bf16x8 kf = *(const bf16x8*)(kr + ds * 16);
                sv = __builtin_amdgcn_mfma_f32_32x32x16_bf16(kf, qf[ds], sv, 0, 0, 0);
            }
        }

        const bool full = (kb >= qb + 31 - w) && (kb + 31 <= qb + w)
                       && (kb + 31 <= T_SEQ - 1);
        float s2[16];
        if (full) {
            #pragma unroll
            for (int r = 0; r < 16; ++r) s2[r] = sv[r] * C2;
        } else {
            const int base = kb - i + w;
            #pragma unroll
            for (int r = 0; r < 16; ++r) {
                const int kr = (r & 3) + 8 * (r >> 2) + 4 * half;
                const unsigned jrel = (unsigned)(base + kr);
                s2[r] = (jrel <= span) ? sv[r] * C2 : -1e9f;
            }
        }

        float mx = s2[0];
        #pragma unroll
        for (int r = 1; r < 16; ++r) mx = fmaxf(mx, s2[r]);
        mx = fmaxf(mx, __shfl_xor(mx, 32, 64));

        if (!__all(mx <= m2 + 8.0f)) {
            const float mnew  = fmaxf(m2, mx);
            const float scale = exp2f(m2 - mnew);
            m2 = mnew;
            l *= scale;
            oa0 *= scale;
            oa1 *= scale;
        }

        float p[16];
        float ps = 0.f;
        #pragma unroll
        for (int r = 0; r < 16; ++r) { p[r] = exp2f(s2[r] - m2); ps += p[r]; }
        ps += __shfl_xor(ps, 32, 64);
        l += ps;

        unsigned pk[8];
        #pragma unroll
        for (int t = 0; t < 8; ++t) {
            union { unsigned u; __bf16 h[2]; } cv;
            cv.h[0] = (__bf16)p[2 * t];
            cv.h[1] = (__bf16)p[2 * t + 1];
            pk[t] = cv.u;
        }
        unsigned y[8];
        #pragma unroll
        for (int t = 0; t < 8; ++t)
            y[t] = (unsigned)__shfl_xor((int)pk[t], 32, 64);

        union { unsigned u[4]; bf16x8 v; } pa0, pa1;
        if (half == 0) {
            pa0.u[0] = pk[0]; pa0.u[1] = pk[1]; pa0.u[2] = y[0];  pa0.u[3] = y[1];
            pa1.u[0] = pk[4]; pa1.u[1] = pk[5]; pa1.u[2] = y[4];  pa1.u[3] = y[5];
        } else {
            pa0.u[0] = y[2];  pa0.u[1] = y[3];  pa0.u[2] = pk[2]; pa0.u[3] = pk[3];
            pa1.u[0] = y[6];  pa1.u[1] = y[7];  pa1.u[2] = pk[6]; pa1.u[3] = pk[7];
        }

        #pragma unroll
        for (int ks = 0; ks < 2; ++ks) {
            const int kc = kb + ks * 16 + half * 8;
            #pragma unroll
            for (int dh = 0; dh < 2; ++dh) {
                const bf16x8 vf = *(const bf16x8*)(Vb + (((size_t)(dh * 32 + ql)) << 10) + kc);
                if (dh == 0)
                    oa0 = __builtin_amdgcn_mfma_f32_32x32x16_bf16(vf, ks ? pa1.v : pa0.v, oa0, 0, 0, 0);
                else
                    oa1 = __builtin_amdgcn_mfma_f32_32x32x16_bf16(vf, ks ? pa1.v : pa0.v, oa1, 0, 0, 0);
            }
        }
    }

    if (i < T_SEQ) {
        const float ri = 1.f / l;
        __bf16* orow = o + (size_t)(b * T_SEQ + i) * DMODEL + hh * DHEAD;
        #pragma unroll
        for (int g = 0; g < 4; ++g) {
            bf16x4 v0, v1;
            #pragma unroll
            for (int r = 0; r < 4; ++r) {
                v0[r] = (__bf16)(oa0[g * 4 + r] * ri);
                v1[r] = (__bf16)(oa1[g * 4 + r] * ri);
            }
            *(bf16x4*)(orow + g * 8 + half * 4)      = v0;
            *(bf16x4*)(orow + 32 + g * 8 + half * 4) = v1;
        }
    }
}

// ---------------------------------------------------------------------------
// h = LayerNorm(h + t) * g + b — bf16 residual stream, fp32 math.
// ---------------------------------------------------------------------------
__global__ __launch_bounds__(256)
void add_ln(__bf16* __restrict__ hb, const __bf16* __restrict__ tbuf,
            const float* __restrict__ g, const float* __restrict__ b)
{
    const int row  = blockIdx.x * 4 + (threadIdx.x >> 6);
    const int lane = threadIdx.x & 63;
    __bf16*       hp = hb   + (size_t)row * DMODEL + lane * 8;
    const __bf16* tp = tbuf + (size_t)row * DMODEL + lane * 8;

    bf16x8 hv = *(const bf16x8*)hp;
    bf16x8 tv = *(const bf16x8*)tp;
    float xv[8];
    #pragma unroll
    for (int j = 0; j < 8; ++j) xv[j] = (float)hv[j] + (float)tv[j];

    float s = 0.f;
    #pragma unroll
    for (int j = 0; j < 8; ++j) s += xv[j];
    #pragma unroll
    for (int off = 32; off >= 1; off >>= 1) s += __shfl_xor(s, off, 64);
    float mean = s * (1.f / DMODEL);

    float vs = 0.f;
    #pragma unroll
    for (int j = 0; j < 8; ++j) { float d = xv[j] - mean; vs += d * d; }
    #pragma unroll
    for (int off = 32; off >= 1; off >>= 1) vs += __shfl_xor(vs, off, 64);
    float rstd = rsqrtf(vs * (1.f / DMODEL) + 1e-5f);

    float4 g0 = *(const float4*)(g + lane * 8);
    float4 g1 = *(const float4*)(g + lane * 8 + 4);
    float4 b0 = *(const float4*)(b + lane * 8);
    float4 b1 = *(const float4*)(b + lane * 8 + 4);
    float gg[8] = {g0.x, g0.y, g0.z, g0.w, g1.x, g1.y, g1.z, g1.w};
    float bb[8] = {b0.x, b0.y, b0.z, b0.w, b1.x, b1.y, b1.z, b1.w};

    bf16x8 ob;
    #pragma unroll
    for (int j = 0; j < 8; ++j)
        ob[j] = (__bf16)((xv[j] - mean) * rstd * gg[j] + bb[j]);
    *(bf16x8*)hp = ob;
}

// ---------------------------------------------------------------------------
__global__ __launch_bounds__(256)
void pool_p1(const __bf16* __restrict__ hb, float* __restrict__ part)
{
    const int bb  = blockIdx.x;
    const int tc  = blockIdx.y;
    const int tid = threadIdx.x;
    const int t0  = tc * (T_SEQ / TCHUNK);
    const __bf16* p = hb + ((size_t)bb * T_SEQ + t0) * DMODEL;

    float mx0 = -3.4e38f, mx1 = -3.4e38f;
    for (int t = 0; t < T_SEQ / TCHUNK; ++t) {
        mx0 = fmaxf(mx0, (float)p[(size_t)t * DMODEL + tid]);
        mx1 = fmaxf(mx1, (float)p[(size_t)t * DMODEL + 256 + tid]);
    }
    float* q = part + ((size_t)bb * TCHUNK + tc) * DMODEL;
    q[tid]       = mx0;
    q[tid + 256] = mx1;
}

// ---------------------------------------------------------------------------
__global__ __launch_bounds__(256)
void pool_p2(const float* __restrict__ part, const float* __restrict__ Wcls,
             const float* __restrict__ bcls, float* __restrict__ out)
{
    __shared__ float pooled[DMODEL];
    __shared__ float logits[8];
    const int bb  = blockIdx.x;
    const int tid = threadIdx.x;

    const float* q = part + (size_t)bb * TCHUNK * DMODEL;
    #pragma unroll
    for (int u = 0; u < 2; ++u) {
        const int d = tid + u * 256;
        float mx = -3.4e38f;
        for (int c = 0; c < TCHUNK; ++c) mx = fmaxf(mx, q[(size_t)c * DMODEL + d]);
        pooled[d] = mx;
    }
    __syncthreads();

    const int cls  = tid >> 5;
    const int lsub = tid & 31;
    const float* wr = Wcls + cls * DMODEL;
    float s = 0.f;
    #pragma unroll
    for (int u = 0; u < 16; ++u) {
        const int d = lsub + u * 32;
        s = fmaf(pooled[d], wr[d], s);
    }
    #pragma unroll
    for (int off = 16; off >= 1; off >>= 1) s += __shfl_xor(s, off, 32);
    if (lsub == 0) logits[cls] = s + bcls[cls];
    __syncthreads();

    if (tid == 0) {
        float mx = logits[0];
        for (int c = 1; c < 8; ++c) mx = fmaxf(mx, logits[c]);
        float se = 0.f;
        for (int c = 0; c < 8; ++c) se += expf(logits[c] - mx);
        float lse = logf(se) + mx;
        for (int c = 0; c < 8; ++c) out[bb * 8 + c] = logits[c] - lse;
    }
}

// ---------------------------------------------------------------------------
extern "C" void kernel_launch(void* const* d_in, const int* in_sizes, int n_in,
                              void* d_out, int out_size, void* d_ws, size_t ws_size,
                              hipStream_t stream)
{
    const float* x    = (const float*)d_in[0];
    const float* Wemb = (const float*)d_in[1];
    const float* bemb = (const float*)d_in[2];
    const float* Wqkv = (const float*)d_in[3];
    const float* bqkv = (const float*)d_in[4];
    const float* Wo   = (const float*)d_in[5];
    const float* bo   = (const float*)d_in[6];
    const float* W1   = (const float*)d_in[7];
    const float* b1f  = (const float*)d_in[8];
    const float* W2   = (const float*)d_in[9];
    const float* b2f  = (const float*)d_in[10];
    const float* g1   = (const float*)d_in[11];
    const float* be1  = (const float*)d_in[12];
    const float* g2   = (const float*)d_in[13];
    const float* be2  = (const float*)d_in[14];
    const float* Wcls = (const float*)d_in[15];
    const float* bcls = (const float*)d_in[16];
    float* out = (float*)d_out;

    // -------- workspace layout (all bf16 except pool partials) --------
    __bf16* hb   = (__bf16*)d_ws;                      // 8000x512
    __bf16* qkb  = hb   + (size_t)MROWS * DMODEL;      // 8000x1024 (Q|K)
    __bf16* vtb  = qkb  + (size_t)MROWS * QKS;         // 8x512x1024 transposed V
    __bf16* attb = vtb  + (size_t)BATCH * DMODEL * VTS;// 8000x512
    __bf16* ff1b = attb + (size_t)MROWS * DMODEL;      // 8000x2048
    __bf16* tmpB = ff1b + (size_t)MROWS * FFDIM;       // 8000x512
    __bf16* xb   = tmpB + (size_t)MROWS * DMODEL;      // 8000x256
    __bf16* wEmb = xb   + (size_t)MROWS * 256;
    __bf16* wQKV = wEmb + 512 * 256;
    __bf16* wWo  = wQKV + (size_t)NLAYER * 3 * DMODEL * DMODEL;
    __bf16* wW1  = wWo  + (size_t)NLAYER * DMODEL * DMODEL;
    __bf16* wW2  = wW1  + (size_t)NLAYER * FFDIM * DMODEL;
    float*  partF = (float*)(wW2 + (size_t)NLAYER * DMODEL * FFDIM); // 8x25x512

    dim3 blk(256);

    // single consolidated fp32->bf16 conversion launch (prefix-sum segments)
    {
        F2BFArgs a;
        const float* srcs[6] = {x, Wemb, Wqkv, Wo, W1, W2};
        __bf16*      dsts[6] = {xb, wEmb, wQKV, wWo, wW1, wW2};
        const int    nbs[6]  = {MROWS * 256 / 1024, 512 * 256 / 1024,
                                NLAYER * 3 * DMODEL * DMODEL / 1024,
                                NLAYER * DMODEL * DMODEL / 1024,
                                NLAYER * FFDIM * DMODEL / 1024,
                                NLAYER * DMODEL * FFDIM / 1024};
        a.off[0] = 0;
        for (int s = 0; s < 6; ++s) {
            a.src[s] = srcs[s];
            a.dst[s] = dsts[s];
            a.off[s + 1] = a.off[s] + nbs[s];
        }
        f2bf_all<<<dim3(a.off[6]), blk, 0, stream>>>(a);
    }

    // embed + fused PE -> hb
    gemm_bf16<1, false><<<dim3(4, 125), blk, 0, stream>>>(
        xb, wEmb, bemb, hb, nullptr, MROWS, DMODEL, 256);

    for (int l = 0; l < NLAYER; ++l) {
        gemm_bf16<2, false><<<dim3(12, 125), blk, 0, stream>>>(
            hb, wQKV + (size_t)l * 3 * DMODEL * DMODEL, bqkv + (size_t)l * 3 * DMODEL,
            qkb, vtb, MROWS, 3 * DMODEL, DMODEL);
        attn_mfma<<<dim3(2048), dim3(64), 0, stream>>>(qkb, vtb, attb);
        gemm_bf16<0, false><<<dim3(4, 125), blk, 0, stream>>>(
            attb, wWo + (size_t)l * DMODEL * DMODEL, bo + (size_t)l * DMODEL,
            tmpB, nullptr, MROWS, DMODEL, DMODEL);
        add_ln<<<dim3(MROWS / 4), blk, 0, stream>>>(
            hb, tmpB, g1 + (size_t)l * DMODEL, be1 + (size_t)l * DMODEL);
        gemm_bf16<0, true><<<dim3(16, 125), blk, 0, stream>>>(
            hb, wW1 + (size_t)l * FFDIM * DMODEL, b1f + (size_t)l * FFDIM,
            ff1b, nullptr, MROWS, FFDIM, DMODEL);
        gemm_bf16<0, false><<<dim3(4, 125), blk, 0, stream>>>(
            ff1b, wW2 + (size_t)l * DMODEL * FFDIM, b2f + (size_t)l * DMODEL,
            tmpB, nullptr, MROWS, DMODEL, FFDIM);
        add_ln<<<dim3(MROWS / 4), blk, 0, stream>>>(
            hb, tmpB, g2 + (size_t)l * DMODEL, be2 + (size_t)l * DMODEL);
    }

    pool_p1<<<dim3(BATCH, TCHUNK), blk, 0, stream>>>(hb, partF);
    pool_p2<<<dim3(BATCH), blk, 0, stream>>>(partF, Wcls, bcls, out);
}